// Round 1
// baseline (77.130 us; speedup 1.0000x reference)
//
#include <hip/hip_runtime.h>
#include <math.h>

#define Bn 32
#define Cn 256
#define Hn 64
#define Wn 64
#define HWn (Hn * Wn)          /* 4096 */
#define CHWn (Cn * HWn)        /* 1048576 */

// ---------------------------------------------------------------------------
// Kernel 1: channel-wise max & mean pooling.
// One block per (b, h) row. 256 threads = 16 channel-groups x 16 float4 cols.
// Each thread reduces 16 channels for its float4 column, then LDS tree-reduce
// across the channel-group axis (strides 128..16 preserve the column index).
// ---------------------------------------------------------------------------
__global__ __launch_bounds__(256) void pool_kernel(const float* __restrict__ X,
                                                   float* __restrict__ maxp,
                                                   float* __restrict__ avgp) {
    const int tid   = threadIdx.x;
    const int w4    = tid & 15;    // float4 column within the row (0..15)
    const int c_sub = tid >> 4;    // channel group (0..15)
    const int b     = blockIdx.x >> 6;
    const int h     = blockIdx.x & 63;

    const float4* Xb = (const float4*)(X + (size_t)b * CHWn + (size_t)h * Wn) + w4;

    float4 mx = make_float4(-INFINITY, -INFINITY, -INFINITY, -INFINITY);
    float4 sm = make_float4(0.f, 0.f, 0.f, 0.f);
    #pragma unroll
    for (int k = 0; k < 16; ++k) {
        const int c = c_sub * 16 + k;
        float4 v = Xb[(size_t)c * (HWn / 4)];
        mx.x = fmaxf(mx.x, v.x); mx.y = fmaxf(mx.y, v.y);
        mx.z = fmaxf(mx.z, v.z); mx.w = fmaxf(mx.w, v.w);
        sm.x += v.x; sm.y += v.y; sm.z += v.z; sm.w += v.w;
    }

    __shared__ float4 smax[256];
    __shared__ float4 ssum[256];
    smax[tid] = mx;
    ssum[tid] = sm;
    __syncthreads();

    #pragma unroll
    for (int s = 128; s >= 16; s >>= 1) {
        if (tid < s) {
            float4 a = smax[tid], c = smax[tid + s];
            a.x = fmaxf(a.x, c.x); a.y = fmaxf(a.y, c.y);
            a.z = fmaxf(a.z, c.z); a.w = fmaxf(a.w, c.w);
            smax[tid] = a;
            float4 p = ssum[tid], q = ssum[tid + s];
            p.x += q.x; p.y += q.y; p.z += q.z; p.w += q.w;
            ssum[tid] = p;
        }
        __syncthreads();
    }

    if (tid < 16) {
        float4 m = smax[tid];
        float4 s4 = ssum[tid];
        const float inv = 1.0f / (float)Cn;
        float4 a = make_float4(s4.x * inv, s4.y * inv, s4.z * inv, s4.w * inv);
        const int o = b * (HWn / 4) + h * 16 + tid;
        ((float4*)maxp)[o] = m;
        ((float4*)avgp)[o] = a;
    }
}

// ---------------------------------------------------------------------------
// Kernel 2: 7x7 conv (2 in-ch: max, avg) + bias + sigmoid -> gate[b, h, w].
// One thread per output pixel; weights staged into LDS.
// ---------------------------------------------------------------------------
__global__ __launch_bounds__(256) void conv_kernel(const float* __restrict__ maxp,
                                                   const float* __restrict__ avgp,
                                                   const float* __restrict__ wgt,  // 98 = 2*7*7 (OIHW)
                                                   const float* __restrict__ bias, // 1
                                                   float* __restrict__ gate) {
    __shared__ float ws[98];
    const int tid = threadIdx.x;
    if (tid < 98) ws[tid] = wgt[tid];
    __syncthreads();

    const int idx = blockIdx.x * 256 + tid;       // 0 .. B*H*W-1
    const int b = idx >> 12;
    const int y = (idx >> 6) & 63;
    const int x = idx & 63;

    const float* mp = maxp + b * HWn;
    const float* ap = avgp + b * HWn;

    float acc = bias[0];
    #pragma unroll
    for (int i = 0; i < 7; ++i) {
        const int yy = y + i - 3;
        if (yy < 0 || yy >= Hn) continue;
        #pragma unroll
        for (int j = 0; j < 7; ++j) {
            const int xx = x + j - 3;
            if (xx < 0 || xx >= Wn) continue;
            const int o = yy * Wn + xx;
            acc += ws[i * 7 + j] * mp[o] + ws[49 + i * 7 + j] * ap[o];
        }
    }
    gate[idx] = 1.0f / (1.0f + expf(-acc));
}

// ---------------------------------------------------------------------------
// Kernel 3: out[b,c,h,w] = gate[b,h,w] * X[b,c,h,w]  (float4, grid-stride)
// ---------------------------------------------------------------------------
__global__ __launch_bounds__(256) void scale_kernel(const float* __restrict__ X,
                                                    const float* __restrict__ gate,
                                                    float* __restrict__ out) {
    const float4* X4 = (const float4*)X;
    const float4* G4 = (const float4*)gate;
    float4* O4 = (float4*)out;
    const int total4 = Bn * CHWn / 4;   // 8388608
    const int step = gridDim.x * blockDim.x;
    for (int v = blockIdx.x * blockDim.x + threadIdx.x; v < total4; v += step) {
        const int hw4 = v & 1023;          // float4 index within the image plane
        const int b   = v >> 18;           // v / (C*HW/4)
        float4 g = G4[b * 1024 + hw4];
        float4 x = X4[v];
        O4[v] = make_float4(g.x * x.x, g.y * x.y, g.z * x.z, g.w * x.w);
    }
}

extern "C" void kernel_launch(void* const* d_in, const int* in_sizes, int n_in,
                              void* d_out, int out_size, void* d_ws, size_t ws_size,
                              hipStream_t stream) {
    const float* X      = (const float*)d_in[0];
    const float* conv_w = (const float*)d_in[1];
    const float* conv_b = (const float*)d_in[2];
    float* out = (float*)d_out;

    // workspace: maxp | avgp | gate  (each B*H*W floats = 512 KiB)
    float* maxp = (float*)d_ws;
    float* avgp = maxp + Bn * HWn;
    float* gate = avgp + Bn * HWn;

    // 1) pooling: one block per (b, h) row
    pool_kernel<<<Bn * Hn, 256, 0, stream>>>(X, maxp, avgp);

    // 2) conv + sigmoid: one thread per pixel
    conv_kernel<<<(Bn * HWn) / 256, 256, 0, stream>>>(maxp, avgp, conv_w, conv_b, gate);

    // 3) broadcast multiply
    scale_kernel<<<2048, 256, 0, stream>>>(X, gate, out);
}

// Round 3
// 73.729 us; speedup vs baseline: 1.0461x; 1.0461x over previous
//
#include <hip/hip_runtime.h>
#include <math.h>

#define Bn 32
#define Cn 256
#define Hn 64
#define Wn 64
#define HWn (Hn * Wn)          /* 4096 */
#define CHWn (Cn * HWn)        /* 1048576 */

typedef float f32x4 __attribute__((ext_vector_type(4)));

// ---------------------------------------------------------------------------
// Kernel 1: channel-wise max & mean pooling.
// One block per (b, h) row. 256 threads = 16 channel-groups x 16 float4 cols.
// Each thread reduces 16 channels for its float4 column, then LDS tree-reduce
// across the channel-group axis (strides 128..16 preserve the column index).
// ---------------------------------------------------------------------------
__global__ __launch_bounds__(256) void pool_kernel(const float* __restrict__ X,
                                                   float* __restrict__ maxp,
                                                   float* __restrict__ avgp) {
    const int tid   = threadIdx.x;
    const int w4    = tid & 15;    // float4 column within the row (0..15)
    const int c_sub = tid >> 4;    // channel group (0..15)
    const int b     = blockIdx.x >> 6;
    const int h     = blockIdx.x & 63;

    const f32x4* Xb = (const f32x4*)(X + (size_t)b * CHWn + (size_t)h * Wn) + w4;

    f32x4 mx = { -INFINITY, -INFINITY, -INFINITY, -INFINITY };
    f32x4 sm = { 0.f, 0.f, 0.f, 0.f };
    #pragma unroll
    for (int k = 0; k < 16; ++k) {
        const int c = c_sub * 16 + k;
        f32x4 v = Xb[(size_t)c * (HWn / 4)];
        mx.x = fmaxf(mx.x, v.x); mx.y = fmaxf(mx.y, v.y);
        mx.z = fmaxf(mx.z, v.z); mx.w = fmaxf(mx.w, v.w);
        sm += v;
    }

    __shared__ f32x4 smax[256];
    __shared__ f32x4 ssum[256];
    smax[tid] = mx;
    ssum[tid] = sm;
    __syncthreads();

    #pragma unroll
    for (int s = 128; s >= 16; s >>= 1) {
        if (tid < s) {
            f32x4 a = smax[tid], c = smax[tid + s];
            a.x = fmaxf(a.x, c.x); a.y = fmaxf(a.y, c.y);
            a.z = fmaxf(a.z, c.z); a.w = fmaxf(a.w, c.w);
            smax[tid] = a;
            ssum[tid] += ssum[tid + s];
        }
        __syncthreads();
    }

    if (tid < 16) {
        f32x4 m = smax[tid];
        f32x4 a = ssum[tid] * (1.0f / (float)Cn);
        const int o = b * (HWn / 4) + h * 16 + tid;
        ((f32x4*)maxp)[o] = m;
        ((f32x4*)avgp)[o] = a;
    }
}

// ---------------------------------------------------------------------------
// Kernel 2 (fused): 7x7 conv + bias + sigmoid -> gate (LDS), then
// out[b,c,h,:] = gate[h,:] * X[b,c,h,:] for all 256 channels.
// One block per (b, h) row. Gate computed by lanes 0..63 from the pooled maps
// (512 KiB total -> L2 resident); scaling streams 64 KB in + 64 KB out.
// Nontemporal loads on X (last use) and stores on out (never re-read) to
// keep X resident in the 256 MiB Infinity Cache across the two passes.
// ---------------------------------------------------------------------------
__global__ __launch_bounds__(256) void conv_scale_kernel(const float* __restrict__ X,
                                                         const float* __restrict__ maxp,
                                                         const float* __restrict__ avgp,
                                                         const float* __restrict__ wgt,  // 98 (OIHW)
                                                         const float* __restrict__ bias, // 1
                                                         float* __restrict__ out) {
    __shared__ float ws[98];
    __shared__ float gate[64];

    const int tid = threadIdx.x;
    const int b = blockIdx.x >> 6;
    const int h = blockIdx.x & 63;

    if (tid < 98) ws[tid] = wgt[tid];
    __syncthreads();

    if (tid < 64) {
        const int x = tid;
        const float* mp = maxp + b * HWn;
        const float* ap = avgp + b * HWn;
        float acc = bias[0];
        #pragma unroll
        for (int i = 0; i < 7; ++i) {
            const int yy = h + i - 3;
            if (yy < 0 || yy >= Hn) continue;
            #pragma unroll
            for (int j = 0; j < 7; ++j) {
                const int xx = x + j - 3;
                if (xx < 0 || xx >= Wn) continue;
                const int o = yy * Wn + xx;
                acc += ws[i * 7 + j] * mp[o] + ws[49 + i * 7 + j] * ap[o];
            }
        }
        gate[x] = 1.0f / (1.0f + expf(-acc));
    }
    __syncthreads();

    // ---- scale: 256 channels x 16 float4 columns = 4096 float4 per block ----
    const int w4 = tid & 15;          // float4 column (constant per thread)
    const int c0 = tid >> 4;          // channel subgroup (0..15)
    const f32x4 g = ((const f32x4*)gate)[w4];   // 2-way LDS aliasing: free

    const f32x4* X4 = (const f32x4*)(X   + (size_t)b * CHWn + (size_t)h * Wn) + w4;
    f32x4*       O4 = (f32x4*)      (out + (size_t)b * CHWn + (size_t)h * Wn) + w4;

    #pragma unroll
    for (int k = 0; k < 16; ++k) {
        const int c = k * 16 + c0;
        const size_t off = (size_t)c * (HWn / 4);
        f32x4 v = __builtin_nontemporal_load(X4 + off);
        v *= g;
        __builtin_nontemporal_store(v, O4 + off);
    }
}

extern "C" void kernel_launch(void* const* d_in, const int* in_sizes, int n_in,
                              void* d_out, int out_size, void* d_ws, size_t ws_size,
                              hipStream_t stream) {
    const float* X      = (const float*)d_in[0];
    const float* conv_w = (const float*)d_in[1];
    const float* conv_b = (const float*)d_in[2];
    float* out = (float*)d_out;

    // workspace: maxp | avgp  (each B*H*W floats = 512 KiB)
    float* maxp = (float*)d_ws;
    float* avgp = maxp + Bn * HWn;

    // 1) pooling: one block per (b, h) row
    pool_kernel<<<Bn * Hn, 256, 0, stream>>>(X, maxp, avgp);

    // 2) conv + sigmoid + broadcast multiply, fused
    conv_scale_kernel<<<Bn * Hn, 256, 0, stream>>>(X, maxp, avgp, conv_w, conv_b, out);
}

// Round 4
// 68.322 us; speedup vs baseline: 1.1289x; 1.0791x over previous
//
#include <hip/hip_runtime.h>
#include <math.h>

#define Bn 32
#define Cn 256
#define Hn 64
#define Wn 64
#define HWn (Hn * Wn)          /* 4096 */
#define CHWn (Cn * HWn)        /* 1048576 */

typedef float f32x4 __attribute__((ext_vector_type(4)));

// ---------------------------------------------------------------------------
// Kernel 1: channel-wise max & mean pooling.
// One block per (b, h) row. 256 threads = 16 channel-groups x 16 float4 cols.
// Each thread reduces 16 channels for its float4 column, then LDS tree-reduce
// across the channel-group axis (strides 128..16 preserve the column index).
// ---------------------------------------------------------------------------
__global__ __launch_bounds__(256) void pool_kernel(const float* __restrict__ X,
                                                   float* __restrict__ maxp,
                                                   float* __restrict__ avgp) {
    const int tid   = threadIdx.x;
    const int w4    = tid & 15;    // float4 column within the row (0..15)
    const int c_sub = tid >> 4;    // channel group (0..15)
    const int b     = blockIdx.x >> 6;
    const int h     = blockIdx.x & 63;

    const f32x4* Xb = (const f32x4*)(X + (size_t)b * CHWn + (size_t)h * Wn) + w4;

    f32x4 mx = { -INFINITY, -INFINITY, -INFINITY, -INFINITY };
    f32x4 sm = { 0.f, 0.f, 0.f, 0.f };
    #pragma unroll
    for (int k = 0; k < 16; ++k) {
        const int c = c_sub * 16 + k;
        f32x4 v = Xb[(size_t)c * (HWn / 4)];
        mx.x = fmaxf(mx.x, v.x); mx.y = fmaxf(mx.y, v.y);
        mx.z = fmaxf(mx.z, v.z); mx.w = fmaxf(mx.w, v.w);
        sm += v;
    }

    __shared__ f32x4 smax[256];
    __shared__ f32x4 ssum[256];
    smax[tid] = mx;
    ssum[tid] = sm;
    __syncthreads();

    #pragma unroll
    for (int s = 128; s >= 16; s >>= 1) {
        if (tid < s) {
            f32x4 a = smax[tid], c = smax[tid + s];
            a.x = fmaxf(a.x, c.x); a.y = fmaxf(a.y, c.y);
            a.z = fmaxf(a.z, c.z); a.w = fmaxf(a.w, c.w);
            smax[tid] = a;
            ssum[tid] += ssum[tid + s];
        }
        __syncthreads();
    }

    if (tid < 16) {
        f32x4 m = smax[tid];
        f32x4 a = ssum[tid] * (1.0f / (float)Cn);
        const int o = b * (HWn / 4) + h * 16 + tid;
        ((f32x4*)maxp)[o] = m;
        ((f32x4*)avgp)[o] = a;
    }
}

// ---------------------------------------------------------------------------
// Kernel 2 (fused): 7x7 conv + bias + sigmoid -> gate (LDS), then
// out[b,c,h,:] = gate[h,:] * X[b,c,h,:] for all 256 channels.
// One block per (b, h) row. Conv is split across all 4 waves (wave g takes
// kernel rows g and g+4), partials combined in LDS. No nontemporal hints:
// in steady-state replays X (read 2x/iter) should stay L3-resident by LRU
// and dirty `out` lines can coalesce in L3 across replays.
// ---------------------------------------------------------------------------
__global__ __launch_bounds__(256) void conv_scale_kernel(const float* __restrict__ X,
                                                         const float* __restrict__ maxp,
                                                         const float* __restrict__ avgp,
                                                         const float* __restrict__ wgt,  // 98 (OIHW)
                                                         const float* __restrict__ bias, // 1
                                                         float* __restrict__ out) {
    __shared__ float ws[98];
    __shared__ float part[4][64];
    __shared__ float gate[64];

    const int tid = threadIdx.x;
    const int b = blockIdx.x >> 6;
    const int h = blockIdx.x & 63;

    if (tid < 98) ws[tid] = wgt[tid];
    __syncthreads();

    // conv partials: wave g handles kernel rows {g, g+4}; pixel x = tid & 63
    {
        const int x = tid & 63;
        const int g = tid >> 6;
        const float* mp = maxp + b * HWn;
        const float* ap = avgp + b * HWn;
        float acc = 0.f;
        #pragma unroll
        for (int ii = 0; ii < 2; ++ii) {
            const int i = g + ii * 4;          // rows 0..6 (g=3,ii=1 -> 7: skip)
            if (i > 6) continue;
            const int yy = h + i - 3;
            if (yy < 0 || yy >= Hn) continue;
            #pragma unroll
            for (int j = 0; j < 7; ++j) {
                const int xx = x + j - 3;
                if (xx < 0 || xx >= Wn) continue;
                const int o = yy * Wn + xx;
                acc += ws[i * 7 + j] * mp[o] + ws[49 + i * 7 + j] * ap[o];
            }
        }
        part[g][x] = acc;
    }
    __syncthreads();

    if (tid < 64) {
        const float acc = bias[0] + part[0][tid] + part[1][tid] + part[2][tid] + part[3][tid];
        gate[tid] = 1.0f / (1.0f + expf(-acc));
    }
    __syncthreads();

    // ---- scale: 256 channels x 16 float4 columns = 4096 float4 per block ----
    const int w4 = tid & 15;          // float4 column (constant per thread)
    const int c0 = tid >> 4;          // channel subgroup (0..15)
    const f32x4 g = ((const f32x4*)gate)[w4];   // 2-way LDS aliasing: free

    const f32x4* X4 = (const f32x4*)(X   + (size_t)b * CHWn + (size_t)h * Wn) + w4;
    f32x4*       O4 = (f32x4*)      (out + (size_t)b * CHWn + (size_t)h * Wn) + w4;

    #pragma unroll
    for (int k = 0; k < 16; ++k) {
        const int c = k * 16 + c0;
        const size_t off = (size_t)c * (HWn / 4);
        f32x4 v = X4[off];
        v *= g;
        O4[off] = v;
    }
}

extern "C" void kernel_launch(void* const* d_in, const int* in_sizes, int n_in,
                              void* d_out, int out_size, void* d_ws, size_t ws_size,
                              hipStream_t stream) {
    const float* X      = (const float*)d_in[0];
    const float* conv_w = (const float*)d_in[1];
    const float* conv_b = (const float*)d_in[2];
    float* out = (float*)d_out;

    // workspace: maxp | avgp  (each B*H*W floats = 512 KiB)
    float* maxp = (float*)d_ws;
    float* avgp = maxp + Bn * HWn;

    // 1) pooling: one block per (b, h) row
    pool_kernel<<<Bn * Hn, 256, 0, stream>>>(X, maxp, avgp);

    // 2) conv + sigmoid + broadcast multiply, fused
    conv_scale_kernel<<<Bn * Hn, 256, 0, stream>>>(X, maxp, avgp, conv_w, conv_b, out);
}

// Round 5
// 68.177 us; speedup vs baseline: 1.1313x; 1.0021x over previous
//
#include <hip/hip_runtime.h>
#include <math.h>

#define Bn 32
#define Cn 256
#define Hn 64
#define Wn 64
#define HWn (Hn * Wn)          /* 4096 */
#define CHWn (Cn * HWn)        /* 1048576 */

typedef float f32x4 __attribute__((ext_vector_type(4)));

// ---------------------------------------------------------------------------
// Kernel 1: channel-wise max & mean pooling.
// One block per (b, h) row. 256 threads = 16 channel-groups x 16 float4 cols.
// Each thread reduces 16 channels for its float4 column, then LDS tree-reduce
// across the channel-group axis (strides 128..16 preserve the column index).
// Normal (cached) loads: this pass warms the 256 MiB Infinity Cache with all
// of X (134 MiB), which kernel 2 re-reads.
// ---------------------------------------------------------------------------
__global__ __launch_bounds__(256) void pool_kernel(const float* __restrict__ X,
                                                   float* __restrict__ maxp,
                                                   float* __restrict__ avgp) {
    const int tid   = threadIdx.x;
    const int w4    = tid & 15;    // float4 column within the row (0..15)
    const int c_sub = tid >> 4;    // channel group (0..15)
    const int b     = blockIdx.x >> 6;
    const int h     = blockIdx.x & 63;

    const f32x4* Xb = (const f32x4*)(X + (size_t)b * CHWn + (size_t)h * Wn) + w4;

    f32x4 mx = { -INFINITY, -INFINITY, -INFINITY, -INFINITY };
    f32x4 sm = { 0.f, 0.f, 0.f, 0.f };
    #pragma unroll
    for (int k = 0; k < 16; ++k) {
        const int c = c_sub * 16 + k;
        f32x4 v = Xb[(size_t)c * (HWn / 4)];
        mx.x = fmaxf(mx.x, v.x); mx.y = fmaxf(mx.y, v.y);
        mx.z = fmaxf(mx.z, v.z); mx.w = fmaxf(mx.w, v.w);
        sm += v;
    }

    __shared__ f32x4 smax[256];
    __shared__ f32x4 ssum[256];
    smax[tid] = mx;
    ssum[tid] = sm;
    __syncthreads();

    #pragma unroll
    for (int s = 128; s >= 16; s >>= 1) {
        if (tid < s) {
            f32x4 a = smax[tid], c = smax[tid + s];
            a.x = fmaxf(a.x, c.x); a.y = fmaxf(a.y, c.y);
            a.z = fmaxf(a.z, c.z); a.w = fmaxf(a.w, c.w);
            smax[tid] = a;
            ssum[tid] += ssum[tid + s];
        }
        __syncthreads();
    }

    if (tid < 16) {
        f32x4 m = smax[tid];
        f32x4 a = ssum[tid] * (1.0f / (float)Cn);
        const int o = b * (HWn / 4) + h * 16 + tid;
        ((f32x4*)maxp)[o] = m;
        ((f32x4*)avgp)[o] = a;
    }
}

// ---------------------------------------------------------------------------
// Kernel 2 (fused): 7x7 conv + bias + sigmoid -> gate (LDS), then
// out[b,c,h,:] = gate[h,:] * X[b,c,h,:] for all 256 channels.
// One block per (b, h) row. Conv split across the 4 waves.
// X loads are NORMAL (should hit L3, warmed by pool); out stores are
// NONTEMPORAL so the 134 MiB write stream does not write-allocate over the
// L3-resident X.
// ---------------------------------------------------------------------------
__global__ __launch_bounds__(256) void conv_scale_kernel(const float* __restrict__ X,
                                                         const float* __restrict__ maxp,
                                                         const float* __restrict__ avgp,
                                                         const float* __restrict__ wgt,  // 98 (OIHW)
                                                         const float* __restrict__ bias, // 1
                                                         float* __restrict__ out) {
    __shared__ float ws[98];
    __shared__ float part[4][64];
    __shared__ float gate[64];

    const int tid = threadIdx.x;
    const int b = blockIdx.x >> 6;
    const int h = blockIdx.x & 63;

    if (tid < 98) ws[tid] = wgt[tid];
    __syncthreads();

    // conv partials: wave g handles kernel rows {g, g+4}; pixel x = tid & 63
    {
        const int x = tid & 63;
        const int g = tid >> 6;
        const float* mp = maxp + b * HWn;
        const float* ap = avgp + b * HWn;
        float acc = 0.f;
        #pragma unroll
        for (int ii = 0; ii < 2; ++ii) {
            const int i = g + ii * 4;          // rows 0..6 (g=3,ii=1 -> 7: skip)
            if (i > 6) continue;
            const int yy = h + i - 3;
            if (yy < 0 || yy >= Hn) continue;
            #pragma unroll
            for (int j = 0; j < 7; ++j) {
                const int xx = x + j - 3;
                if (xx < 0 || xx >= Wn) continue;
                const int o = yy * Wn + xx;
                acc += ws[i * 7 + j] * mp[o] + ws[49 + i * 7 + j] * ap[o];
            }
        }
        part[g][x] = acc;
    }
    __syncthreads();

    if (tid < 64) {
        const float acc = bias[0] + part[0][tid] + part[1][tid] + part[2][tid] + part[3][tid];
        gate[tid] = 1.0f / (1.0f + expf(-acc));
    }
    __syncthreads();

    // ---- scale: 256 channels x 16 float4 columns = 4096 float4 per block ----
    const int w4 = tid & 15;          // float4 column (constant per thread)
    const int c0 = tid >> 4;          // channel subgroup (0..15)
    const f32x4 g = ((const f32x4*)gate)[w4];   // 2-way LDS aliasing: free

    const f32x4* X4 = (const f32x4*)(X   + (size_t)b * CHWn + (size_t)h * Wn) + w4;
    f32x4*       O4 = (f32x4*)      (out + (size_t)b * CHWn + (size_t)h * Wn) + w4;

    #pragma unroll
    for (int k = 0; k < 16; ++k) {
        const int c = k * 16 + c0;
        const size_t off = (size_t)c * (HWn / 4);
        f32x4 v = X4[off];              // normal load: L3 hit expected
        v *= g;
        __builtin_nontemporal_store(v, O4 + off);   // streaming store
    }
}

extern "C" void kernel_launch(void* const* d_in, const int* in_sizes, int n_in,
                              void* d_out, int out_size, void* d_ws, size_t ws_size,
                              hipStream_t stream) {
    const float* X      = (const float*)d_in[0];
    const float* conv_w = (const float*)d_in[1];
    const float* conv_b = (const float*)d_in[2];
    float* out = (float*)d_out;

    // workspace: maxp | avgp  (each B*H*W floats = 512 KiB)
    float* maxp = (float*)d_ws;
    float* avgp = maxp + Bn * HWn;

    // 1) pooling: one block per (b, h) row
    pool_kernel<<<Bn * Hn, 256, 0, stream>>>(X, maxp, avgp);

    // 2) conv + sigmoid + broadcast multiply, fused
    conv_scale_kernel<<<Bn * Hn, 256, 0, stream>>>(X, maxp, avgp, conv_w, conv_b, out);
}